// Round 12
// baseline (111.203 us; speedup 1.0000x reference)
//
#include <hip/hip_runtime.h>
#include <hip/hip_bf16.h>

#define HID 768
#define PD 164
#define NQ 196
#define SEQ 2048

typedef __attribute__((ext_vector_type(8))) short bf16x8_t;
typedef __attribute__((ext_vector_type(4))) float f32x4_t;
typedef __attribute__((ext_vector_type(16))) float f32x16_t;
typedef __attribute__((ext_vector_type(4))) unsigned int u32x4_t;

static __device__ __forceinline__ unsigned short f2bfu(float f) {
  union { __hip_bfloat16 h; unsigned short u; } cv;
  cv.h = __float2bfloat16(f);
  return cv.u;
}

static __device__ __forceinline__ unsigned cvtpk(float a, float b) {
  unsigned r;
  asm("v_cvt_pk_bf16_f32 %0, %1, %2" : "=v"(r) : "v"(a), "v"(b));
  return r;
}

static __device__ __forceinline__ void gload16(const void* g, void* l) {
  __builtin_amdgcn_global_load_lds(
      (const __attribute__((address_space(1))) void*)g,
      (__attribute__((address_space(3))) void*)l, 16, 0, 0);
}

// ---------------- prep: weights -> bf16 ----------------
__global__ __launch_bounds__(256) void k_prep(const float* __restrict__ qkv_w,
                                              const float* __restrict__ out_w,
                                              unsigned short* __restrict__ qwb,
                                              unsigned short* __restrict__ wb) {
  int bid = blockIdx.x;
  if (bid < 576) {
    int i = (bid * 256 + threadIdx.x) * 4;   // 768*768 = 589824 elems
    float4 v = *(const float4*)(out_w + i);
    ushort4 o;
    o.x = f2bfu(v.x); o.y = f2bfu(v.y); o.z = f2bfu(v.z); o.w = f2bfu(v.w);
    *(ushort4*)(wb + i) = o;
  } else {
    int i = ((bid - 576) * 256 + threadIdx.x) * 4;  // 208*192 = 39936 elems
    int n = i / 192, k = i - n * 192;
    float v0 = (n < NQ && k + 0 < PD) ? qkv_w[n * PD + k + 0] : 0.f;
    float v1 = (n < NQ && k + 1 < PD) ? qkv_w[n * PD + k + 1] : 0.f;
    float v2 = (n < NQ && k + 2 < PD) ? qkv_w[n * PD + k + 2] : 0.f;
    float v3 = (n < NQ && k + 3 < PD) ? qkv_w[n * PD + k + 3] : 0.f;
    ushort4 o;
    o.x = f2bfu(v0); o.y = f2bfu(v1); o.z = f2bfu(v2); o.w = f2bfu(v3);
    *(ushort4*)(qwb + i) = o;
  }
}

// ---------------- fused LN + x2 convert + QKV GEMM ----------------
__global__ __launch_bounds__(256, 2) void k_lnqkv(const float* __restrict__ hidden,
                                                  const float* __restrict__ lns,
                                                  const float* __restrict__ lnb,
                                                  const unsigned short* __restrict__ qwb,
                                                  const float* __restrict__ qkv_b,
                                                  unsigned short* __restrict__ merged,
                                                  unsigned short* __restrict__ qg,
                                                  unsigned short* __restrict__ kg,
                                                  unsigned short* __restrict__ v16) {
  __shared__ float xr[64][172];
  __shared__ float stats[64][2];
  __shared__ unsigned short Aq[64][200];   // x1n bf16; cols 164..191 zero
  int t = threadIdx.x;
  int r0 = blockIdx.x * 64;
  #pragma unroll
  for (int i = 0; i < 11; i++) {
    int idx = t + i * 256;                 // 64 rows * 41 quads = 2624
    if (idx < 2624) {
      int row = idx / 41, q = idx - row * 41;
      float4 v = *(const float4*)(hidden + (size_t)(r0 + row) * HID + q * 4);
      *(float4*)&xr[row][q * 4] = v;
    }
  }
  __syncthreads();
  {
    int l = t & 63, w = t >> 6;
    int row = w * 16 + (l & 15), g = l >> 4;
    float sum = 0.f, sq = 0.f;
    #pragma unroll
    for (int j = 0; j < 41; j++) {
      float x = xr[row][g * 41 + j];
      sum += x; sq += x * x;
    }
    sum += __shfl_xor(sum, 16, 64); sum += __shfl_xor(sum, 32, 64);
    sq  += __shfl_xor(sq, 16, 64);  sq  += __shfl_xor(sq, 32, 64);
    float mean = sum * (1.f / PD);
    float var = sq * (1.f / PD) - mean * mean;
    float rstd = rsqrtf(var + 1e-5f);
    if (g == 0) { stats[row][0] = mean; stats[row][1] = rstd; }
  }
  __syncthreads();
  #pragma unroll
  for (int i = 0; i < 24; i++) {
    int idx = t + i * 256;                 // 64 rows * 96 pairs (192 cols)
    int row = idx / 96, c2 = idx - row * 96;
    int d = c2 * 2;
    float mean = stats[row][0], rstd = stats[row][1];
    float v0 = (d < PD)     ? (xr[row][d]     - mean) * rstd * lns[d]     + lnb[d]     : 0.f;
    float v1 = (d + 1 < PD) ? (xr[row][d + 1] - mean) * rstd * lns[d + 1] + lnb[d + 1] : 0.f;
    unsigned int pk = (unsigned int)f2bfu(v0) | ((unsigned int)f2bfu(v1) << 16);
    *(unsigned int*)(&Aq[row][d]) = pk;
  }
  #pragma unroll
  for (int i = 0; i < 38; i++) {
    int idx = t + i * 256;                 // 64 rows * 151 quads = 9664
    if (idx < 9664) {
      int row = idx / 151, q = idx - row * 151;
      int d = PD + q * 4;
      float4 v = *(const float4*)(hidden + (size_t)(r0 + row) * HID + d);
      ushort4 o;
      o.x = f2bfu(v.x); o.y = f2bfu(v.y); o.z = f2bfu(v.z); o.w = f2bfu(v.w);
      *(ushort4*)(merged + (size_t)(r0 + row) * HID + d) = o;
    }
  }
  __syncthreads();
  // ---- QKV GEMM: A from LDS, B from L2 ----
  int l = t & 63, w = t >> 6, lr15 = l & 15, g = l >> 4;
  f32x4_t acc[13];
  #pragma unroll
  for (int n = 0; n < 13; n++) acc[n] = (f32x4_t){0.f, 0.f, 0.f, 0.f};
  #pragma unroll 2
  for (int kc = 0; kc < 6; kc++) {
    bf16x8_t a = *(const bf16x8_t*)(&Aq[w * 16 + lr15][kc * 32 + g * 8]);
    #pragma unroll
    for (int n = 0; n < 13; n++) {
      bf16x8_t b = *(const bf16x8_t*)(qwb + (size_t)(n * 16 + lr15) * 192 + kc * 32 + g * 8);
      acc[n] = __builtin_amdgcn_mfma_f32_16x16x32_bf16(a, b, acc[n], 0, 0, 0);
    }
  }
  // ---- epilogue ----
  {
    float bias = qkv_b[lr15];
    #pragma unroll
    for (int r = 0; r < 4; r++) {
      int grow = r0 + w * 16 + g * 4 + r;
      qg[(size_t)grow * 16 + lr15] = f2bfu((acc[0][r] + bias) * 0.36067376022224085f); // 0.25*log2(e)
    }
  }
  {
    float bias = qkv_b[16 + lr15];
    #pragma unroll
    for (int r = 0; r < 4; r++) {
      int grow = r0 + w * 16 + g * 4 + r;
      kg[(size_t)grow * 16 + lr15] = f2bfu(acc[1][r] + bias);
    }
  }
  int s0 = (r0 & 2047) + w * 16;
  int bb = r0 >> 11;
  size_t vrowbase = (size_t)(bb * 128 + (s0 >> 4)) * 192;
  #pragma unroll
  for (int n = 2; n < 13; n++) {
    int col = n * 16 + lr15;
    int d = col - 32;                      // 0..175
    float bias = (col < NQ) ? qkv_b[col] : 0.f;
    float v0 = acc[n][0] + bias, v1 = acc[n][1] + bias;
    float v2 = acc[n][2] + bias, v3 = acc[n][3] + bias;
    if (d == 164) { v0 = v1 = v2 = v3 = 1.f; }        // ones row: free denominator
    else if (d >= PD) { v0 = v1 = v2 = v3 = 0.f; }
    ushort4 o;
    o.x = f2bfu(v0); o.y = f2bfu(v1); o.z = f2bfu(v2); o.w = f2bfu(v3);
    *(ushort4*)(v16 + (vrowbase + d) * 16 + g * 4) = o;
  }
}

// ---------------- flash attention v5 (unchanged) ----------------
__global__ __launch_bounds__(256, 2) void k_attn(const unsigned short* __restrict__ qg,
                                                 const unsigned short* __restrict__ kg,
                                                 const unsigned short* __restrict__ v16,
                                                 unsigned short* __restrict__ merged) {
  __shared__ float red[2][64 * 98];
  int t = threadIdx.x;
  int w = t >> 6, l = t & 63;
  int b = blockIdx.x & 7, qt = blockIdx.x >> 3;
  int lo = l & 31, hi = l >> 5;
  int qbase = b * SEQ + qt * 32;
  bf16x8_t qf = *(const bf16x8_t*)(qg + (size_t)(qbase + lo) * 16 + hi * 8);
  const unsigned short* kb = kg + (size_t)b * SEQ * 16;
  const unsigned short* vbb = v16 + (size_t)b * 128 * 192 * 16;
  f32x16_t zro;
  #pragma unroll
  for (int r = 0; r < 16; r++) zro[r] = 0.f;
  f32x16_t acc[6];
  #pragma unroll
  for (int f = 0; f < 6; f++) acc[f] = zro;

  int it0 = w * 8;
  bf16x8_t kf0 = *(const bf16x8_t*)(kb + (size_t)(it0 * 64 + lo) * 16 + hi * 8);
  bf16x8_t kf1 = *(const bf16x8_t*)(kb + (size_t)(it0 * 64 + 32 + lo) * 16 + hi * 8);
  bf16x8_t va[6], vb_[6];
  {
    const unsigned short* vt0 = vbb + (size_t)(it0 * 4) * (192 * 16) + hi * 8;
    #pragma unroll
    for (int f = 0; f < 6; f++) va[f] = *(const bf16x8_t*)(vt0 + (f * 32 + lo) * 16);
  }
  for (int it = it0; it < it0 + 8; ++it) {
    bf16x8_t nk0 = *(const bf16x8_t*)(kb + (size_t)((it + 1) * 64 + lo) * 16 + hi * 8);
    bf16x8_t nk1 = *(const bf16x8_t*)(kb + (size_t)((it + 1) * 64 + 32 + lo) * 16 + hi * 8);
    f32x16_t sc0 = __builtin_amdgcn_mfma_f32_32x32x16_bf16(kf0, qf, zro, 0, 0, 0);
    f32x16_t sc1 = __builtin_amdgcn_mfma_f32_32x32x16_bf16(kf1, qf, zro, 0, 0, 0);
    bf16x8_t pa[4];
    #pragma unroll
    for (int jt = 0; jt < 2; ++jt) {
      f32x16_t sc = jt ? sc1 : sc0;
      unsigned u[8];
      #pragma unroll
      for (int k = 0; k < 8; ++k)
        u[k] = cvtpk(exp2f(sc[2 * k]), exp2f(sc[2 * k + 1]));
      asm volatile("v_permlane32_swap_b32 %0, %1" : "+v"(u[0]), "+v"(u[2]));
      asm volatile("v_permlane32_swap_b32 %0, %1" : "+v"(u[1]), "+v"(u[3]));
      asm volatile("v_permlane32_swap_b32 %0, %1" : "+v"(u[4]), "+v"(u[6]));
      asm volatile("v_permlane32_swap_b32 %0, %1" : "+v"(u[5]), "+v"(u[7]));
      union { u32x4_t u4; bf16x8_t h8; } c0, c1;
      c0.u4 = (u32x4_t){u[0], u[1], u[2], u[3]};
      c1.u4 = (u32x4_t){u[4], u[5], u[6], u[7]};
      pa[jt * 2 + 0] = c0.h8;
      pa[jt * 2 + 1] = c1.h8;
    }
#define PV_STEP(JS, VCUR, VNXT, NT, NJS)                                            \
    {                                                                               \
      const unsigned short* vtn = vbb + (size_t)((NT) * 4 + (NJS)) * (192 * 16) + hi * 8; \
      _Pragma("unroll")                                                             \
      for (int f = 0; f < 6; f++) VNXT[f] = *(const bf16x8_t*)(vtn + (f * 32 + lo) * 16); \
      _Pragma("unroll")                                                             \
      for (int f = 0; f < 6; f++)                                                   \
        acc[f] = __builtin_amdgcn_mfma_f32_32x32x16_bf16(pa[JS], VCUR[f], acc[f], 0, 0, 0); \
    }
    PV_STEP(0, va,  vb_, it, 1)
    PV_STEP(1, vb_, va,  it, 2)
    PV_STEP(2, va,  vb_, it, 3)
    PV_STEP(3, vb_, va,  it + 1, 0)
#undef PV_STEP
    kf0 = nk0; kf1 = nk1;
  }

  if (w >= 2) {
    float* dst = &red[w - 2][l * 98];
    #pragma unroll
    for (int f = 0; f < 6; f++)
      #pragma unroll
      for (int r = 0; r < 16; r += 2)
        *(float2*)(dst + f * 16 + r) = make_float2(acc[f][r], acc[f][r + 1]);
  }
  __syncthreads();
  if (w < 2) {
    const float* src = &red[w][l * 98];
    #pragma unroll
    for (int f = 0; f < 6; f++)
      #pragma unroll
      for (int r = 0; r < 16; r += 2) {
        float2 v = *(const float2*)(src + f * 16 + r);
        acc[f][r] += v.x; acc[f][r + 1] += v.y;
      }
  }
  __syncthreads();
  if (w == 1) {
    float* dst = &red[0][l * 98];
    #pragma unroll
    for (int f = 0; f < 6; f++)
      #pragma unroll
      for (int r = 0; r < 16; r += 2)
        *(float2*)(dst + f * 16 + r) = make_float2(acc[f][r], acc[f][r + 1]);
  }
  __syncthreads();
  if (w == 0) {
    const float* src = &red[0][l * 98];
    #pragma unroll
    for (int f = 0; f < 6; f++)
      #pragma unroll
      for (int r = 0; r < 16; r += 2) {
        float2 v = *(const float2*)(src + f * 16 + r);
        acc[f][r] += v.x; acc[f][r + 1] += v.y;
      }
    float dninv[16];
    #pragma unroll
    for (int r = 0; r < 16; ++r)
      dninv[r] = 1.0f / __shfl(acc[5][r], 4 + hi * 32, 64);
    #pragma unroll
    for (int f = 0; f < 6; ++f) {
      int d = f * 32 + lo;
      if (d < PD) {
        #pragma unroll
        for (int r = 0; r < 16; ++r) {
          int q = qbase + (r & 3) + 8 * (r >> 2) + 4 * hi;
          merged[(size_t)q * HID + d] = f2bfu(acc[f][r] * dninv[r]);
        }
      }
    }
  }
}

// ---------------- out GEMM v6: 1-wave blocks, ZERO barriers --------------------
// 64 threads/block, 64x64 tile, BK=32, private 16 KB dbuf LDS -> 10 blocks/CU.
// Wave-scoped pipeline: counted vmcnt(8) replaces barrier #1 (stage landed);
// lgkmcnt(0) before re-stage replaces barrier #2 (reads drained). No cross-wave sync.
// Grid 3072 = 8 XCDs x 384, n-major (12 nb / mb) for A-panel L2 reuse. R11 swizzle.
__global__ __launch_bounds__(64) void k_out(const unsigned short* __restrict__ mg,
                                            const unsigned short* __restrict__ wb,
                                            const float* __restrict__ out_b,
                                            float* __restrict__ out) {
  __shared__ unsigned short Al[2][64 * 32];    // 8 KB
  __shared__ unsigned short Bl[2][64 * 32];    // 8 KB
  int l = threadIdx.x;
  int bid = blockIdx.x;
  int wgid = (bid & 7) * 384 + (bid >> 3);     // bijective: 3072 = 8*384
  int nb = wgid % 12, mb = wgid / 12;
  int m0 = mb * 64, n0 = nb * 64;
  int lr = l & 15, lg = l >> 4;
  int sw = (lr >> 1) & 3;
  f32x4_t acc[4][4];
  #pragma unroll
  for (int mi = 0; mi < 4; mi++)
    #pragma unroll
    for (int ni = 0; ni < 4; ni++) acc[mi][ni] = (f32x4_t){0.f, 0.f, 0.f, 0.f};

  auto stage = [&](int buf, int kt) {          // 4 A + 4 B gload16 per lane
    #pragma unroll
    for (int i = 0; i < 4; i++) {
      int off = l + i * 64;                    // 256 chunks = 64x32 bf16
      int row = off >> 2, c = off & 3;
      int cs = c ^ ((row >> 1) & 3);           // inverse swizzle on SOURCE
      gload16(mg + (size_t)(m0 + row) * HID + kt * 32 + cs * 8, (char*)&Al[buf][0] + off * 16);
    }
    #pragma unroll
    for (int i = 0; i < 4; i++) {
      int off = l + i * 64;
      int row = off >> 2, c = off & 3;
      int cs = c ^ ((row >> 1) & 3);
      gload16(wb + (size_t)(n0 + row) * HID + kt * 32 + cs * 8, (char*)&Bl[buf][0] + off * 16);
    }
  };
  auto compute = [&](int cur) {                // 16 MFMAs (K=32)
    bf16x8_t a[4], bfr[4];
    int slot = lg ^ sw;
    #pragma unroll
    for (int mi = 0; mi < 4; mi++)
      a[mi] = *(const bf16x8_t*)(&Al[cur][(mi * 16 + lr) * 32 + slot * 8]);
    #pragma unroll
    for (int ni = 0; ni < 4; ni++)
      bfr[ni] = *(const bf16x8_t*)(&Bl[cur][(ni * 16 + lr) * 32 + slot * 8]);
    #pragma unroll
    for (int mi = 0; mi < 4; mi++)
      #pragma unroll
      for (int ni = 0; ni < 4; ni++)
        acc[mi][ni] = __builtin_amdgcn_mfma_f32_16x16x32_bf16(a[mi], bfr[ni], acc[mi][ni], 0, 0, 0);
  };

  stage(0, 0);
  stage(1, 1);                                 // 16 loads in flight
  for (int kt = 0; kt < 23; kt++) {
    int cur = kt & 1;
    asm volatile("s_waitcnt vmcnt(8)" ::: "memory");     // stage(kt) landed; stage(kt+1) in flight
    compute(cur);
    asm volatile("s_waitcnt lgkmcnt(0)" ::: "memory");   // my ds_reads of buf[cur] drained
    if (kt + 2 < 24) stage(cur, kt + 2);                 // overwrite buf[cur] for kt+2
  }
  asm volatile("s_waitcnt vmcnt(0)" ::: "memory");
  compute(1);                                  // kt = 23

  #pragma unroll
  for (int ni = 0; ni < 4; ni++) {
    int col = n0 + ni * 16 + lr;
    float bias = out_b[col];
    #pragma unroll
    for (int mi = 0; mi < 4; mi++) {
      #pragma unroll
      for (int r = 0; r < 4; r++) {
        int row = m0 + mi * 16 + lg * 4 + r;
        out[(size_t)row * HID + col] = acc[mi][ni][r] + bias;
      }
    }
  }
}

extern "C" void kernel_launch(void* const* d_in, const int* in_sizes, int n_in,
                              void* d_out, int out_size, void* d_ws, size_t ws_size,
                              hipStream_t stream) {
  const float* hidden = (const float*)d_in[0];
  const float* lns    = (const float*)d_in[1];
  const float* lnb    = (const float*)d_in[2];
  const float* qkv_w  = (const float*)d_in[3];
  const float* qkv_b  = (const float*)d_in[4];
  const float* out_w  = (const float*)d_in[5];
  const float* out_b  = (const float*)d_in[6];
  char* ws = (char*)d_ws;
  unsigned short* qg  = (unsigned short*)(ws + 0);          // 16384*16*2      =   524288
  unsigned short* kg  = (unsigned short*)(ws + 524288);     // 16384*16*2      =   524288
  unsigned short* v16 = (unsigned short*)(ws + 1048576);    // 8*128*192*16*2  =  6291456
  unsigned short* qwb = (unsigned short*)(ws + 13631488);   // 208*192*2       =    79872
  unsigned short* wb  = (unsigned short*)(ws + 13711360);   // 768*768*2       =  1179648
  unsigned short* mg  = (unsigned short*)(ws + 14891008);   // 16384*768*2     = 25165824 (end 40056832)
  hipLaunchKernelGGL(k_prep,  dim3(615), dim3(256), 0, stream, qkv_w, out_w, qwb, wb);
  hipLaunchKernelGGL(k_lnqkv, dim3(256), dim3(256), 0, stream, hidden, lns, lnb, qwb, qkv_b,
                     mg, qg, kg, v16);
  hipLaunchKernelGGL(k_attn,  dim3(512), dim3(256), 0, stream, qg, kg, v16, mg);
  hipLaunchKernelGGL(k_out,   dim3(3072), dim3(64), 0, stream, mg, wb, out_b, (float*)d_out);
}

// Round 13
// 101.327 us; speedup vs baseline: 1.0975x; 1.0975x over previous
//
#include <hip/hip_runtime.h>
#include <hip/hip_bf16.h>

#define HID 768
#define PD 164
#define NQ 196
#define SEQ 2048

typedef __attribute__((ext_vector_type(8))) short bf16x8_t;
typedef __attribute__((ext_vector_type(4))) float f32x4_t;
typedef __attribute__((ext_vector_type(16))) float f32x16_t;
typedef __attribute__((ext_vector_type(4))) unsigned int u32x4_t;

static __device__ __forceinline__ unsigned short f2bfu(float f) {
  union { __hip_bfloat16 h; unsigned short u; } cv;
  cv.h = __float2bfloat16(f);
  return cv.u;
}

static __device__ __forceinline__ unsigned cvtpk(float a, float b) {
  unsigned r;
  asm("v_cvt_pk_bf16_f32 %0, %1, %2" : "=v"(r) : "v"(a), "v"(b));
  return r;
}

static __device__ __forceinline__ void gload16(const void* g, void* l) {
  __builtin_amdgcn_global_load_lds(
      (const __attribute__((address_space(1))) void*)g,
      (__attribute__((address_space(3))) void*)l, 16, 0, 0);
}

// ---------------- prep: weights -> bf16 ----------------
__global__ __launch_bounds__(256) void k_prep(const float* __restrict__ qkv_w,
                                              const float* __restrict__ out_w,
                                              unsigned short* __restrict__ qwb,
                                              unsigned short* __restrict__ wb) {
  int bid = blockIdx.x;
  if (bid < 576) {
    int i = (bid * 256 + threadIdx.x) * 4;   // 768*768 = 589824 elems
    float4 v = *(const float4*)(out_w + i);
    ushort4 o;
    o.x = f2bfu(v.x); o.y = f2bfu(v.y); o.z = f2bfu(v.z); o.w = f2bfu(v.w);
    *(ushort4*)(wb + i) = o;
  } else {
    int i = ((bid - 576) * 256 + threadIdx.x) * 4;  // 208*192 = 39936 elems
    int n = i / 192, k = i - n * 192;
    float v0 = (n < NQ && k + 0 < PD) ? qkv_w[n * PD + k + 0] : 0.f;
    float v1 = (n < NQ && k + 1 < PD) ? qkv_w[n * PD + k + 1] : 0.f;
    float v2 = (n < NQ && k + 2 < PD) ? qkv_w[n * PD + k + 2] : 0.f;
    float v3 = (n < NQ && k + 3 < PD) ? qkv_w[n * PD + k + 3] : 0.f;
    ushort4 o;
    o.x = f2bfu(v0); o.y = f2bfu(v1); o.z = f2bfu(v2); o.w = f2bfu(v3);
    *(ushort4*)(qwb + i) = o;
  }
}

// ---------------- fused LN + x2 convert + QKV GEMM ----------------
__global__ __launch_bounds__(256, 2) void k_lnqkv(const float* __restrict__ hidden,
                                                  const float* __restrict__ lns,
                                                  const float* __restrict__ lnb,
                                                  const unsigned short* __restrict__ qwb,
                                                  const float* __restrict__ qkv_b,
                                                  unsigned short* __restrict__ merged,
                                                  unsigned short* __restrict__ qg,
                                                  unsigned short* __restrict__ kg,
                                                  unsigned short* __restrict__ v16) {
  __shared__ float xr[64][172];
  __shared__ float stats[64][2];
  __shared__ unsigned short Aq[64][200];   // x1n bf16; cols 164..191 zero
  int t = threadIdx.x;
  int r0 = blockIdx.x * 64;
  #pragma unroll
  for (int i = 0; i < 11; i++) {
    int idx = t + i * 256;                 // 64 rows * 41 quads = 2624
    if (idx < 2624) {
      int row = idx / 41, q = idx - row * 41;
      float4 v = *(const float4*)(hidden + (size_t)(r0 + row) * HID + q * 4);
      *(float4*)&xr[row][q * 4] = v;
    }
  }
  __syncthreads();
  {
    int l = t & 63, w = t >> 6;
    int row = w * 16 + (l & 15), g = l >> 4;
    float sum = 0.f, sq = 0.f;
    #pragma unroll
    for (int j = 0; j < 41; j++) {
      float x = xr[row][g * 41 + j];
      sum += x; sq += x * x;
    }
    sum += __shfl_xor(sum, 16, 64); sum += __shfl_xor(sum, 32, 64);
    sq  += __shfl_xor(sq, 16, 64);  sq  += __shfl_xor(sq, 32, 64);
    float mean = sum * (1.f / PD);
    float var = sq * (1.f / PD) - mean * mean;
    float rstd = rsqrtf(var + 1e-5f);
    if (g == 0) { stats[row][0] = mean; stats[row][1] = rstd; }
  }
  __syncthreads();
  #pragma unroll
  for (int i = 0; i < 24; i++) {
    int idx = t + i * 256;                 // 64 rows * 96 pairs (192 cols)
    int row = idx / 96, c2 = idx - row * 96;
    int d = c2 * 2;
    float mean = stats[row][0], rstd = stats[row][1];
    float v0 = (d < PD)     ? (xr[row][d]     - mean) * rstd * lns[d]     + lnb[d]     : 0.f;
    float v1 = (d + 1 < PD) ? (xr[row][d + 1] - mean) * rstd * lns[d + 1] + lnb[d + 1] : 0.f;
    unsigned int pk = (unsigned int)f2bfu(v0) | ((unsigned int)f2bfu(v1) << 16);
    *(unsigned int*)(&Aq[row][d]) = pk;
  }
  #pragma unroll
  for (int i = 0; i < 38; i++) {
    int idx = t + i * 256;                 // 64 rows * 151 quads = 9664
    if (idx < 9664) {
      int row = idx / 151, q = idx - row * 151;
      int d = PD + q * 4;
      float4 v = *(const float4*)(hidden + (size_t)(r0 + row) * HID + d);
      ushort4 o;
      o.x = f2bfu(v.x); o.y = f2bfu(v.y); o.z = f2bfu(v.z); o.w = f2bfu(v.w);
      *(ushort4*)(merged + (size_t)(r0 + row) * HID + d) = o;
    }
  }
  __syncthreads();
  // ---- QKV GEMM: A from LDS, B from L2 ----
  int l = t & 63, w = t >> 6, lr15 = l & 15, g = l >> 4;
  f32x4_t acc[13];
  #pragma unroll
  for (int n = 0; n < 13; n++) acc[n] = (f32x4_t){0.f, 0.f, 0.f, 0.f};
  #pragma unroll 2
  for (int kc = 0; kc < 6; kc++) {
    bf16x8_t a = *(const bf16x8_t*)(&Aq[w * 16 + lr15][kc * 32 + g * 8]);
    #pragma unroll
    for (int n = 0; n < 13; n++) {
      bf16x8_t b = *(const bf16x8_t*)(qwb + (size_t)(n * 16 + lr15) * 192 + kc * 32 + g * 8);
      acc[n] = __builtin_amdgcn_mfma_f32_16x16x32_bf16(a, b, acc[n], 0, 0, 0);
    }
  }
  // ---- epilogue ----
  {
    float bias = qkv_b[lr15];
    #pragma unroll
    for (int r = 0; r < 4; r++) {
      int grow = r0 + w * 16 + g * 4 + r;
      qg[(size_t)grow * 16 + lr15] = f2bfu((acc[0][r] + bias) * 0.36067376022224085f); // 0.25*log2(e)
    }
  }
  {
    float bias = qkv_b[16 + lr15];
    #pragma unroll
    for (int r = 0; r < 4; r++) {
      int grow = r0 + w * 16 + g * 4 + r;
      kg[(size_t)grow * 16 + lr15] = f2bfu(acc[1][r] + bias);
    }
  }
  int s0 = (r0 & 2047) + w * 16;
  int bb = r0 >> 11;
  size_t vrowbase = (size_t)(bb * 128 + (s0 >> 4)) * 192;
  #pragma unroll
  for (int n = 2; n < 13; n++) {
    int col = n * 16 + lr15;
    int d = col - 32;                      // 0..175
    float bias = (col < NQ) ? qkv_b[col] : 0.f;
    float v0 = acc[n][0] + bias, v1 = acc[n][1] + bias;
    float v2 = acc[n][2] + bias, v3 = acc[n][3] + bias;
    if (d == 164) { v0 = v1 = v2 = v3 = 1.f; }        // ones row: free denominator
    else if (d >= PD) { v0 = v1 = v2 = v3 = 0.f; }
    ushort4 o;
    o.x = f2bfu(v0); o.y = f2bfu(v1); o.z = f2bfu(v2); o.w = f2bfu(v3);
    *(ushort4*)(v16 + (vrowbase + d) * 16 + g * 4) = o;
  }
}

// ---------------- flash attention v7: d-split x2 -> 16 waves/CU ----------------
// 512 blocks (batch = bid&7, q-tile of 32 rows) x 8 waves (512 thr).
// wave w: dh = w&1 (3 of 6 d-frags), jq = w>>1 (8 of 32 j-tiles).
// acc halved to 3 x f32x16 (48 VGPR) -> __launch_bounds__(512,4) targets <=128 VGPR
// = 4 waves/SIMD (2x TLP vs v5). QK + softmax duplicated across the dh pair (cheap).
// Hot loop barrier-free; jq-tree-reduce + dh denominator exchange at the end.
__global__ __launch_bounds__(512, 4) void k_attn(const unsigned short* __restrict__ qg,
                                                 const unsigned short* __restrict__ kg,
                                                 const unsigned short* __restrict__ v16,
                                                 unsigned short* __restrict__ merged) {
  __shared__ float red[4][64 * 50];          // 51.2 KB; 2 blocks/CU fit
  __shared__ float sl[2][16];                // dh=1 -> dh=0 denominator stripe
  int t = threadIdx.x;
  int w = t >> 6, l = t & 63;
  int dh = w & 1, jq = w >> 1;
  int dh3 = dh * 3;
  int b = blockIdx.x & 7, qt = blockIdx.x >> 3;
  int lo = l & 31, hi = l >> 5;
  int qbase = b * SEQ + qt * 32;
  bf16x8_t qf = *(const bf16x8_t*)(qg + (size_t)(qbase + lo) * 16 + hi * 8);
  const unsigned short* kb = kg + (size_t)b * SEQ * 16;
  const unsigned short* vbb = v16 + (size_t)b * 128 * 192 * 16;
  f32x16_t zro;
  #pragma unroll
  for (int r = 0; r < 16; r++) zro[r] = 0.f;
  f32x16_t acc[3];
  #pragma unroll
  for (int f = 0; f < 3; f++) acc[f] = zro;

  int it0 = jq * 8;
  for (int it = it0; it < it0 + 8; ++it) {
    bf16x8_t kf0 = *(const bf16x8_t*)(kb + (size_t)(it * 64 + lo) * 16 + hi * 8);
    bf16x8_t kf1 = *(const bf16x8_t*)(kb + (size_t)(it * 64 + 32 + lo) * 16 + hi * 8);
    // preload js0 V (covered by QK + softmax below)
    bf16x8_t va[3], vb_[3];
    {
      const unsigned short* vt0 = vbb + (size_t)(it * 4) * (192 * 16) + hi * 8;
      #pragma unroll
      for (int f = 0; f < 3; f++) va[f] = *(const bf16x8_t*)(vt0 + ((dh3 + f) * 32 + lo) * 16);
    }
    f32x16_t sc0 = __builtin_amdgcn_mfma_f32_32x32x16_bf16(kf0, qf, zro, 0, 0, 0);
    f32x16_t sc1 = __builtin_amdgcn_mfma_f32_32x32x16_bf16(kf1, qf, zro, 0, 0, 0);
    bf16x8_t pa[4];
    {
      unsigned u[8];
      #pragma unroll
      for (int k = 0; k < 8; ++k)
        u[k] = cvtpk(exp2f(sc0[2 * k]), exp2f(sc0[2 * k + 1]));
      asm volatile("v_permlane32_swap_b32 %0, %1" : "+v"(u[0]), "+v"(u[2]));
      asm volatile("v_permlane32_swap_b32 %0, %1" : "+v"(u[1]), "+v"(u[3]));
      asm volatile("v_permlane32_swap_b32 %0, %1" : "+v"(u[4]), "+v"(u[6]));
      asm volatile("v_permlane32_swap_b32 %0, %1" : "+v"(u[5]), "+v"(u[7]));
      union { u32x4_t u4; bf16x8_t h8; } c0, c1;
      c0.u4 = (u32x4_t){u[0], u[1], u[2], u[3]};
      c1.u4 = (u32x4_t){u[4], u[5], u[6], u[7]};
      pa[0] = c0.h8; pa[1] = c1.h8;
    }
    {
      unsigned u[8];
      #pragma unroll
      for (int k = 0; k < 8; ++k)
        u[k] = cvtpk(exp2f(sc1[2 * k]), exp2f(sc1[2 * k + 1]));
      asm volatile("v_permlane32_swap_b32 %0, %1" : "+v"(u[0]), "+v"(u[2]));
      asm volatile("v_permlane32_swap_b32 %0, %1" : "+v"(u[1]), "+v"(u[3]));
      asm volatile("v_permlane32_swap_b32 %0, %1" : "+v"(u[4]), "+v"(u[6]));
      asm volatile("v_permlane32_swap_b32 %0, %1" : "+v"(u[5]), "+v"(u[7]));
      union { u32x4_t u4; bf16x8_t h8; } c0, c1;
      c0.u4 = (u32x4_t){u[0], u[1], u[2], u[3]};
      c1.u4 = (u32x4_t){u[4], u[5], u[6], u[7]};
      pa[2] = c0.h8; pa[3] = c1.h8;
    }
    // PV: 4 j-subtiles x 3 d-frags (this wave's dh half); V dbuf, next js issued first.
#define PV_STEP(JS, VCUR, VNXT, PREF)                                               \
    {                                                                               \
      if (PREF) {                                                                   \
        const unsigned short* vtn = vbb + (size_t)(it * 4 + (JS) + 1) * (192 * 16) + hi * 8; \
        _Pragma("unroll")                                                           \
        for (int f = 0; f < 3; f++) VNXT[f] = *(const bf16x8_t*)(vtn + ((dh3 + f) * 32 + lo) * 16); \
      }                                                                             \
      _Pragma("unroll")                                                             \
      for (int f = 0; f < 3; f++)                                                   \
        acc[f] = __builtin_amdgcn_mfma_f32_32x32x16_bf16(pa[JS], VCUR[f], acc[f], 0, 0, 0); \
    }
    PV_STEP(0, va,  vb_, 1)
    PV_STEP(1, vb_, va,  1)
    PV_STEP(2, va,  vb_, 1)
    PV_STEP(3, vb_, va,  0)
#undef PV_STEP
  }

  // ---- jq tree reduction (fixed-max softmax: partials add) ----
  if (jq >= 2) {                                 // jq2 -> slot dh, jq3 -> slot 2+dh
    float* dst = &red[(jq - 2) * 2 + dh][l * 50];
    #pragma unroll
    for (int f = 0; f < 3; f++)
      #pragma unroll
      for (int r = 0; r < 16; r += 2)
        *(float2*)(dst + f * 16 + r) = make_float2(acc[f][r], acc[f][r + 1]);
  }
  __syncthreads();
  if (jq <= 1) {
    const float* src = &red[jq * 2 + dh][l * 50];
    #pragma unroll
    for (int f = 0; f < 3; f++)
      #pragma unroll
      for (int r = 0; r < 16; r += 2) {
        float2 v = *(const float2*)(src + f * 16 + r);
        acc[f][r] += v.x; acc[f][r + 1] += v.y;
      }
  }
  if (jq == 1) {                                 // re-store to slot 2+dh
    float* dst = &red[2 + dh][l * 50];
    #pragma unroll
    for (int f = 0; f < 3; f++)
      #pragma unroll
      for (int r = 0; r < 16; r += 2)
        *(float2*)(dst + f * 16 + r) = make_float2(acc[f][r], acc[f][r + 1]);
  }
  __syncthreads();
  float dninv[16];
  if (jq == 0) {
    const float* src = &red[2 + dh][l * 50];
    #pragma unroll
    for (int f = 0; f < 3; f++)
      #pragma unroll
      for (int r = 0; r < 16; r += 2) {
        float2 v = *(const float2*)(src + f * 16 + r);
        acc[f][r] += v.x; acc[f][r + 1] += v.y;
      }
    if (dh == 1) {
      // denominator: local frag 2 = d 160..191; lane lo==4 holds d=164 (ones row)
      #pragma unroll
      for (int r = 0; r < 16; ++r)
        dninv[r] = 1.0f / __shfl(acc[2][r], 4 + hi * 32, 64);
      if (lo == 0) {
        #pragma unroll
        for (int r = 0; r < 16; ++r) sl[hi][r] = dninv[r];
      }
    }
  }
  __syncthreads();
  if (jq == 0) {
    if (dh == 0) {
      #pragma unroll
      for (int r = 0; r < 16; ++r) dninv[r] = sl[hi][r];
    }
    #pragma unroll
    for (int f = 0; f < 3; ++f) {
      int d = (dh3 + f) * 32 + lo;
      if (d < PD) {
        #pragma unroll
        for (int r = 0; r < 16; ++r) {
          int q = qbase + (r & 3) + 8 * (r >> 2) + 4 * hi;
          merged[(size_t)q * HID + d] = f2bfu(acc[f][r] * dninv[r]);
        }
      }
    }
  }
}

// ---------------- out GEMM v5 (R11, proven ~33us — FROZEN) --------------------
// A+B via gload16 (B L2-dedup through LDS), BK=32 -> 32 KB LDS, 3 blocks/CU,
// counted vmcnt(4), raw barriers, T5 setprio, T1 XCD swizzle, rotate-swizzle LDS.
__global__ __launch_bounds__(256, 3) void k_out(const unsigned short* __restrict__ mg,
                                                const unsigned short* __restrict__ wb,
                                                const float* __restrict__ out_b,
                                                float* __restrict__ out) {
  __shared__ unsigned short Al[2][128 * 32];   // 16 KB
  __shared__ unsigned short Bl[2][128 * 32];   // 16 KB
  int t = threadIdx.x;
  int bid = blockIdx.x;
  int wgid = (bid & 7) * 96 + (bid >> 3);      // bijective: 768 = 8*96
  int nb = wgid % 6, mb = wgid / 6;
  int m0 = mb * 128, n0 = nb * 128;
  int l = t & 63, w = t >> 6, wr = w >> 1, wc = w & 1;
  int lr = l & 15, lg = l >> 4;
  int sw = (lr >> 1) & 3;
  f32x4_t acc[4][4];
  #pragma unroll
  for (int mi = 0; mi < 4; mi++)
    #pragma unroll
    for (int ni = 0; ni < 4; ni++) acc[mi][ni] = (f32x4_t){0.f, 0.f, 0.f, 0.f};

  auto stage = [&](int buf, int kt) {          // 2 A + 2 B gload16 per thread
    #pragma unroll
    for (int i = 0; i < 2; i++) {
      int off = t + i * 256;                   // 512 x 16B = 128x32 bf16
      int row = off >> 2, c = off & 3;
      int cs = c ^ ((row >> 1) & 3);           // inverse swizzle on SOURCE
      gload16(mg + (size_t)(m0 + row) * HID + kt * 32 + cs * 8, (char*)&Al[buf][0] + off * 16);
    }
    #pragma unroll
    for (int i = 0; i < 2; i++) {
      int off = t + i * 256;
      int row = off >> 2, c = off & 3;
      int cs = c ^ ((row >> 1) & 3);
      gload16(wb + (size_t)(n0 + row) * HID + kt * 32 + cs * 8, (char*)&Bl[buf][0] + off * 16);
    }
  };
  auto compute = [&](int cur) {                // 16 MFMAs (K=32 per step)
    __builtin_amdgcn_s_setprio(1);
    bf16x8_t a[4], bfr[4];
    int slot = lg ^ sw;
    #pragma unroll
    for (int mi = 0; mi < 4; mi++)
      a[mi] = *(const bf16x8_t*)(&Al[cur][(wr * 64 + mi * 16 + lr) * 32 + slot * 8]);
    #pragma unroll
    for (int ni = 0; ni < 4; ni++)
      bfr[ni] = *(const bf16x8_t*)(&Bl[cur][(wc * 64 + ni * 16 + lr) * 32 + slot * 8]);
    #pragma unroll
    for (int mi = 0; mi < 4; mi++)
      #pragma unroll
      for (int ni = 0; ni < 4; ni++)
        acc[mi][ni] = __builtin_amdgcn_mfma_f32_16x16x32_bf16(a[mi], bfr[ni], acc[mi][ni], 0, 0, 0);
    __builtin_amdgcn_s_setprio(0);
  };

  stage(0, 0);
  stage(1, 1);                                 // 8 loads in flight
  for (int kt = 0; kt < 23; kt++) {
    int cur = kt & 1;
    asm volatile("s_waitcnt vmcnt(4)" ::: "memory");     // stage(kt) landed; stage(kt+1) in flight
    __builtin_amdgcn_sched_barrier(0);
    __builtin_amdgcn_s_barrier();
    compute(cur);
    asm volatile("s_waitcnt lgkmcnt(0)" ::: "memory");   // my ds_reads of buf[cur] done
    __builtin_amdgcn_sched_barrier(0);
    __builtin_amdgcn_s_barrier();
    if (kt + 2 < 24) stage(cur, kt + 2);
  }
  asm volatile("s_waitcnt vmcnt(0)" ::: "memory");
  __builtin_amdgcn_sched_barrier(0);
  __builtin_amdgcn_s_barrier();
  compute(1);                                  // kt = 23

  #pragma unroll
  for (int ni = 0; ni < 4; ni++) {
    int col = n0 + wc * 64 + ni * 16 + lr;
    float bias = out_b[col];
    #pragma unroll
    for (int mi = 0; mi < 4; mi++) {
      #pragma unroll
      for (int r = 0; r < 4; r++) {
        int row = m0 + wr * 64 + mi * 16 + lg * 4 + r;
        out[(size_t)row * HID + col] = acc[mi][ni][r] + bias;
      }
    }
  }
}

extern "C" void kernel_launch(void* const* d_in, const int* in_sizes, int n_in,
                              void* d_out, int out_size, void* d_ws, size_t ws_size,
                              hipStream_t stream) {
  const float* hidden = (const float*)d_in[0];
  const float* lns    = (const float*)d_in[1];
  const float* lnb    = (const float*)d_in[2];
  const float* qkv_w  = (const float*)d_in[3];
  const float* qkv_b  = (const float*)d_in[4];
  const float* out_w  = (const float*)d_in[5];
  const float* out_b  = (const float*)d_in[6];
  char* ws = (char*)d_ws;
  unsigned short* qg  = (unsigned short*)(ws + 0);          // 16384*16*2      =   524288
  unsigned short* kg  = (unsigned short*)(ws + 524288);     // 16384*16*2      =   524288
  unsigned short* v16 = (unsigned short*)(ws + 1048576);    // 8*128*192*16*2  =  6291456
  unsigned short* qwb = (unsigned short*)(ws + 13631488);   // 208*192*2       =    79872
  unsigned short* wb  = (unsigned short*)(ws + 13711360);   // 768*768*2       =  1179648
  unsigned short* mg  = (unsigned short*)(ws + 14891008);   // 16384*768*2     = 25165824 (end 40056832)
  hipLaunchKernelGGL(k_prep,  dim3(615), dim3(256), 0, stream, qkv_w, out_w, qwb, wb);
  hipLaunchKernelGGL(k_lnqkv, dim3(256), dim3(256), 0, stream, hidden, lns, lnb, qwb, qkv_b,
                     mg, qg, kg, v16);
  hipLaunchKernelGGL(k_attn,  dim3(512), dim3(512), 0, stream, qg, kg, v16, mg);
  hipLaunchKernelGGL(k_out,   dim3(768), dim3(256), 0, stream, mg, wb, out_b, (float*)d_out);
}

// Round 14
// 98.206 us; speedup vs baseline: 1.1323x; 1.0318x over previous
//
#include <hip/hip_runtime.h>
#include <hip/hip_bf16.h>

#define HID 768
#define PD 164
#define NQ 196
#define SEQ 2048

typedef __attribute__((ext_vector_type(8))) short bf16x8_t;
typedef __attribute__((ext_vector_type(4))) float f32x4_t;
typedef __attribute__((ext_vector_type(16))) float f32x16_t;
typedef __attribute__((ext_vector_type(4))) unsigned int u32x4_t;

static __device__ __forceinline__ unsigned short f2bfu(float f) {
  union { __hip_bfloat16 h; unsigned short u; } cv;
  cv.h = __float2bfloat16(f);
  return cv.u;
}

static __device__ __forceinline__ unsigned cvtpk(float a, float b) {
  unsigned r;
  asm("v_cvt_pk_bf16_f32 %0, %1, %2" : "=v"(r) : "v"(a), "v"(b));
  return r;
}

static __device__ __forceinline__ void gload16(const void* g, void* l) {
  __builtin_amdgcn_global_load_lds(
      (const __attribute__((address_space(1))) void*)g,
      (__attribute__((address_space(3))) void*)l, 16, 0, 0);
}

// ---------------- prep: weights -> bf16 ----------------
__global__ __launch_bounds__(256) void k_prep(const float* __restrict__ qkv_w,
                                              const float* __restrict__ out_w,
                                              unsigned short* __restrict__ qwb,
                                              unsigned short* __restrict__ wb) {
  int bid = blockIdx.x;
  if (bid < 576) {
    int i = (bid * 256 + threadIdx.x) * 4;   // 768*768 = 589824 elems
    float4 v = *(const float4*)(out_w + i);
    ushort4 o;
    o.x = f2bfu(v.x); o.y = f2bfu(v.y); o.z = f2bfu(v.z); o.w = f2bfu(v.w);
    *(ushort4*)(wb + i) = o;
  } else {
    int i = ((bid - 576) * 256 + threadIdx.x) * 4;  // 208*192 = 39936 elems
    int n = i / 192, k = i - n * 192;
    float v0 = (n < NQ && k + 0 < PD) ? qkv_w[n * PD + k + 0] : 0.f;
    float v1 = (n < NQ && k + 1 < PD) ? qkv_w[n * PD + k + 1] : 0.f;
    float v2 = (n < NQ && k + 2 < PD) ? qkv_w[n * PD + k + 2] : 0.f;
    float v3 = (n < NQ && k + 3 < PD) ? qkv_w[n * PD + k + 3] : 0.f;
    ushort4 o;
    o.x = f2bfu(v0); o.y = f2bfu(v1); o.z = f2bfu(v2); o.w = f2bfu(v3);
    *(ushort4*)(qwb + i) = o;
  }
}

// ---------------- fused LN + x2 convert + QKV GEMM ----------------
__global__ __launch_bounds__(256, 2) void k_lnqkv(const float* __restrict__ hidden,
                                                  const float* __restrict__ lns,
                                                  const float* __restrict__ lnb,
                                                  const unsigned short* __restrict__ qwb,
                                                  const float* __restrict__ qkv_b,
                                                  unsigned short* __restrict__ merged,
                                                  unsigned short* __restrict__ qg,
                                                  unsigned short* __restrict__ kg,
                                                  unsigned short* __restrict__ v16) {
  __shared__ float xr[64][172];
  __shared__ float stats[64][2];
  __shared__ unsigned short Aq[64][200];   // x1n bf16; cols 164..191 zero
  int t = threadIdx.x;
  int r0 = blockIdx.x * 64;
  #pragma unroll
  for (int i = 0; i < 11; i++) {
    int idx = t + i * 256;                 // 64 rows * 41 quads = 2624
    if (idx < 2624) {
      int row = idx / 41, q = idx - row * 41;
      float4 v = *(const float4*)(hidden + (size_t)(r0 + row) * HID + q * 4);
      *(float4*)&xr[row][q * 4] = v;
    }
  }
  __syncthreads();
  {
    int l = t & 63, w = t >> 6;
    int row = w * 16 + (l & 15), g = l >> 4;
    float sum = 0.f, sq = 0.f;
    #pragma unroll
    for (int j = 0; j < 41; j++) {
      float x = xr[row][g * 41 + j];
      sum += x; sq += x * x;
    }
    sum += __shfl_xor(sum, 16, 64); sum += __shfl_xor(sum, 32, 64);
    sq  += __shfl_xor(sq, 16, 64);  sq  += __shfl_xor(sq, 32, 64);
    float mean = sum * (1.f / PD);
    float var = sq * (1.f / PD) - mean * mean;
    float rstd = rsqrtf(var + 1e-5f);
    if (g == 0) { stats[row][0] = mean; stats[row][1] = rstd; }
  }
  __syncthreads();
  #pragma unroll
  for (int i = 0; i < 24; i++) {
    int idx = t + i * 256;                 // 64 rows * 96 pairs (192 cols)
    int row = idx / 96, c2 = idx - row * 96;
    int d = c2 * 2;
    float mean = stats[row][0], rstd = stats[row][1];
    float v0 = (d < PD)     ? (xr[row][d]     - mean) * rstd * lns[d]     + lnb[d]     : 0.f;
    float v1 = (d + 1 < PD) ? (xr[row][d + 1] - mean) * rstd * lns[d + 1] + lnb[d + 1] : 0.f;
    unsigned int pk = (unsigned int)f2bfu(v0) | ((unsigned int)f2bfu(v1) << 16);
    *(unsigned int*)(&Aq[row][d]) = pk;
  }
  #pragma unroll
  for (int i = 0; i < 38; i++) {
    int idx = t + i * 256;                 // 64 rows * 151 quads = 9664
    if (idx < 9664) {
      int row = idx / 151, q = idx - row * 151;
      int d = PD + q * 4;
      float4 v = *(const float4*)(hidden + (size_t)(r0 + row) * HID + d);
      ushort4 o;
      o.x = f2bfu(v.x); o.y = f2bfu(v.y); o.z = f2bfu(v.z); o.w = f2bfu(v.w);
      *(ushort4*)(merged + (size_t)(r0 + row) * HID + d) = o;
    }
  }
  __syncthreads();
  // ---- QKV GEMM: A from LDS, B from L2 ----
  int l = t & 63, w = t >> 6, lr15 = l & 15, g = l >> 4;
  f32x4_t acc[13];
  #pragma unroll
  for (int n = 0; n < 13; n++) acc[n] = (f32x4_t){0.f, 0.f, 0.f, 0.f};
  #pragma unroll 2
  for (int kc = 0; kc < 6; kc++) {
    bf16x8_t a = *(const bf16x8_t*)(&Aq[w * 16 + lr15][kc * 32 + g * 8]);
    #pragma unroll
    for (int n = 0; n < 13; n++) {
      bf16x8_t b = *(const bf16x8_t*)(qwb + (size_t)(n * 16 + lr15) * 192 + kc * 32 + g * 8);
      acc[n] = __builtin_amdgcn_mfma_f32_16x16x32_bf16(a, b, acc[n], 0, 0, 0);
    }
  }
  // ---- epilogue ----
  {
    float bias = qkv_b[lr15];
    #pragma unroll
    for (int r = 0; r < 4; r++) {
      int grow = r0 + w * 16 + g * 4 + r;
      qg[(size_t)grow * 16 + lr15] = f2bfu((acc[0][r] + bias) * 0.36067376022224085f); // 0.25*log2(e)
    }
  }
  {
    float bias = qkv_b[16 + lr15];
    #pragma unroll
    for (int r = 0; r < 4; r++) {
      int grow = r0 + w * 16 + g * 4 + r;
      kg[(size_t)grow * 16 + lr15] = f2bfu(acc[1][r] + bias);
    }
  }
  int s0 = (r0 & 2047) + w * 16;
  int bb = r0 >> 11;
  size_t vrowbase = (size_t)(bb * 128 + (s0 >> 4)) * 192;
  #pragma unroll
  for (int n = 2; n < 13; n++) {
    int col = n * 16 + lr15;
    int d = col - 32;                      // 0..175
    float bias = (col < NQ) ? qkv_b[col] : 0.f;
    float v0 = acc[n][0] + bias, v1 = acc[n][1] + bias;
    float v2 = acc[n][2] + bias, v3 = acc[n][3] + bias;
    if (d == 164) { v0 = v1 = v2 = v3 = 1.f; }        // ones row: free denominator
    else if (d >= PD) { v0 = v1 = v2 = v3 = 0.f; }
    ushort4 o;
    o.x = f2bfu(v0); o.y = f2bfu(v1); o.z = f2bfu(v2); o.w = f2bfu(v3);
    *(ushort4*)(v16 + (vrowbase + d) * 16 + g * 4) = o;
  }
}

// ---------------- flash attention v5 (proven, FROZEN) ----------------
__global__ __launch_bounds__(256, 2) void k_attn(const unsigned short* __restrict__ qg,
                                                 const unsigned short* __restrict__ kg,
                                                 const unsigned short* __restrict__ v16,
                                                 unsigned short* __restrict__ merged) {
  __shared__ float red[2][64 * 98];
  int t = threadIdx.x;
  int w = t >> 6, l = t & 63;
  int b = blockIdx.x & 7, qt = blockIdx.x >> 3;
  int lo = l & 31, hi = l >> 5;
  int qbase = b * SEQ + qt * 32;
  bf16x8_t qf = *(const bf16x8_t*)(qg + (size_t)(qbase + lo) * 16 + hi * 8);
  const unsigned short* kb = kg + (size_t)b * SEQ * 16;
  const unsigned short* vbb = v16 + (size_t)b * 128 * 192 * 16;
  f32x16_t zro;
  #pragma unroll
  for (int r = 0; r < 16; r++) zro[r] = 0.f;
  f32x16_t acc[6];
  #pragma unroll
  for (int f = 0; f < 6; f++) acc[f] = zro;

  int it0 = w * 8;
  bf16x8_t kf0 = *(const bf16x8_t*)(kb + (size_t)(it0 * 64 + lo) * 16 + hi * 8);
  bf16x8_t kf1 = *(const bf16x8_t*)(kb + (size_t)(it0 * 64 + 32 + lo) * 16 + hi * 8);
  bf16x8_t va[6], vb_[6];
  {
    const unsigned short* vt0 = vbb + (size_t)(it0 * 4) * (192 * 16) + hi * 8;
    #pragma unroll
    for (int f = 0; f < 6; f++) va[f] = *(const bf16x8_t*)(vt0 + (f * 32 + lo) * 16);
  }
  for (int it = it0; it < it0 + 8; ++it) {
    bf16x8_t nk0 = *(const bf16x8_t*)(kb + (size_t)((it + 1) * 64 + lo) * 16 + hi * 8);
    bf16x8_t nk1 = *(const bf16x8_t*)(kb + (size_t)((it + 1) * 64 + 32 + lo) * 16 + hi * 8);
    f32x16_t sc0 = __builtin_amdgcn_mfma_f32_32x32x16_bf16(kf0, qf, zro, 0, 0, 0);
    f32x16_t sc1 = __builtin_amdgcn_mfma_f32_32x32x16_bf16(kf1, qf, zro, 0, 0, 0);
    bf16x8_t pa[4];
    #pragma unroll
    for (int jt = 0; jt < 2; ++jt) {
      f32x16_t sc = jt ? sc1 : sc0;
      unsigned u[8];
      #pragma unroll
      for (int k = 0; k < 8; ++k)
        u[k] = cvtpk(exp2f(sc[2 * k]), exp2f(sc[2 * k + 1]));
      asm volatile("v_permlane32_swap_b32 %0, %1" : "+v"(u[0]), "+v"(u[2]));
      asm volatile("v_permlane32_swap_b32 %0, %1" : "+v"(u[1]), "+v"(u[3]));
      asm volatile("v_permlane32_swap_b32 %0, %1" : "+v"(u[4]), "+v"(u[6]));
      asm volatile("v_permlane32_swap_b32 %0, %1" : "+v"(u[5]), "+v"(u[7]));
      union { u32x4_t u4; bf16x8_t h8; } c0, c1;
      c0.u4 = (u32x4_t){u[0], u[1], u[2], u[3]};
      c1.u4 = (u32x4_t){u[4], u[5], u[6], u[7]};
      pa[jt * 2 + 0] = c0.h8;
      pa[jt * 2 + 1] = c1.h8;
    }
#define PV_STEP(JS, VCUR, VNXT, NT, NJS)                                            \
    {                                                                               \
      const unsigned short* vtn = vbb + (size_t)((NT) * 4 + (NJS)) * (192 * 16) + hi * 8; \
      _Pragma("unroll")                                                             \
      for (int f = 0; f < 6; f++) VNXT[f] = *(const bf16x8_t*)(vtn + (f * 32 + lo) * 16); \
      _Pragma("unroll")                                                             \
      for (int f = 0; f < 6; f++)                                                   \
        acc[f] = __builtin_amdgcn_mfma_f32_32x32x16_bf16(pa[JS], VCUR[f], acc[f], 0, 0, 0); \
    }
    PV_STEP(0, va,  vb_, it, 1)
    PV_STEP(1, vb_, va,  it, 2)
    PV_STEP(2, va,  vb_, it, 3)
    PV_STEP(3, vb_, va,  it + 1, 0)
#undef PV_STEP
    kf0 = nk0; kf1 = nk1;
  }

  if (w >= 2) {
    float* dst = &red[w - 2][l * 98];
    #pragma unroll
    for (int f = 0; f < 6; f++)
      #pragma unroll
      for (int r = 0; r < 16; r += 2)
        *(float2*)(dst + f * 16 + r) = make_float2(acc[f][r], acc[f][r + 1]);
  }
  __syncthreads();
  if (w < 2) {
    const float* src = &red[w][l * 98];
    #pragma unroll
    for (int f = 0; f < 6; f++)
      #pragma unroll
      for (int r = 0; r < 16; r += 2) {
        float2 v = *(const float2*)(src + f * 16 + r);
        acc[f][r] += v.x; acc[f][r + 1] += v.y;
      }
  }
  __syncthreads();
  if (w == 1) {
    float* dst = &red[0][l * 98];
    #pragma unroll
    for (int f = 0; f < 6; f++)
      #pragma unroll
      for (int r = 0; r < 16; r += 2)
        *(float2*)(dst + f * 16 + r) = make_float2(acc[f][r], acc[f][r + 1]);
  }
  __syncthreads();
  if (w == 0) {
    const float* src = &red[0][l * 98];
    #pragma unroll
    for (int f = 0; f < 6; f++)
      #pragma unroll
      for (int r = 0; r < 16; r += 2) {
        float2 v = *(const float2*)(src + f * 16 + r);
        acc[f][r] += v.x; acc[f][r + 1] += v.y;
      }
    float dninv[16];
    #pragma unroll
    for (int r = 0; r < 16; ++r)
      dninv[r] = 1.0f / __shfl(acc[5][r], 4 + hi * 32, 64);
    #pragma unroll
    for (int f = 0; f < 6; ++f) {
      int d = f * 32 + lo;
      if (d < PD) {
        #pragma unroll
        for (int r = 0; r < 16; ++r) {
          int q = qbase + (r & 3) + 8 * (r >> 2) + 4 * hi;
          merged[(size_t)q * HID + d] = f2bfu(acc[f][r] * dninv[r]);
        }
      }
    }
  }
}

// ---------------- out GEMM v7: R11 schedule, 32x32x16 MFMA (half the LDS reads) ----
// Same proven pipeline (BK=32, 3 blocks/CU, counted vmcnt(4), raw barriers, setprio,
// XCD swizzle). 8 b128 reads + 8 MFMAs per wave-step (was 16+16 at 16x16x32).
// Swizzle: slot' = slot ^ (row&3); 8 bank-groups x 8 lanes -> conflict-free b128.
// Frag layout verified by k_attn: A/B lane l -> row/col l&31, k=(l>>5)*8+e;
// C: col=l&31, row=(r&3)+8*(r>>2)+4*(l>>5).
__global__ __launch_bounds__(256, 3) void k_out(const unsigned short* __restrict__ mg,
                                                const unsigned short* __restrict__ wb,
                                                const float* __restrict__ out_b,
                                                float* __restrict__ out) {
  __shared__ unsigned short Al[2][128 * 32];   // 16 KB
  __shared__ unsigned short Bl[2][128 * 32];   // 16 KB
  int t = threadIdx.x;
  int bid = blockIdx.x;
  int wgid = (bid & 7) * 96 + (bid >> 3);      // bijective: 768 = 8*96
  int nb = wgid % 6, mb = wgid / 6;
  int m0 = mb * 128, n0 = nb * 128;
  int l = t & 63, w = t >> 6, wr = w >> 1, wc = w & 1;
  int lo = l & 31, hi = l >> 5;
  f32x16_t acc[2][2];
  #pragma unroll
  for (int mi = 0; mi < 2; mi++)
    #pragma unroll
    for (int ni = 0; ni < 2; ni++)
      #pragma unroll
      for (int r = 0; r < 16; r++) acc[mi][ni][r] = 0.f;

  auto stage = [&](int buf, int kt) {          // 2 A + 2 B gload16 per thread
    #pragma unroll
    for (int i = 0; i < 2; i++) {
      int off = t + i * 256;                   // 512 x 16B = 128x32 bf16
      int row = off >> 2, c = off & 3;
      int cs = c ^ (row & 3);                  // inverse swizzle on SOURCE
      gload16(mg + (size_t)(m0 + row) * HID + kt * 32 + cs * 8, (char*)&Al[buf][0] + off * 16);
    }
    #pragma unroll
    for (int i = 0; i < 2; i++) {
      int off = t + i * 256;
      int row = off >> 2, c = off & 3;
      int cs = c ^ (row & 3);
      gload16(wb + (size_t)(n0 + row) * HID + kt * 32 + cs * 8, (char*)&Bl[buf][0] + off * 16);
    }
  };
  auto compute = [&](int cur) {                // 8 MFMAs of 32x32x16 (K=32 per step)
    __builtin_amdgcn_s_setprio(1);
    #pragma unroll
    for (int kc = 0; kc < 2; kc++) {
      bf16x8_t a[2], bfr[2];
      int slot = (kc * 2 + hi) ^ (lo & 3);     // read-side swizzle
      #pragma unroll
      for (int mi = 0; mi < 2; mi++)
        a[mi] = *(const bf16x8_t*)(&Al[cur][(wr * 64 + mi * 32 + lo) * 32 + slot * 8]);
      #pragma unroll
      for (int ni = 0; ni < 2; ni++)
        bfr[ni] = *(const bf16x8_t*)(&Bl[cur][(wc * 64 + ni * 32 + lo) * 32 + slot * 8]);
      #pragma unroll
      for (int mi = 0; mi < 2; mi++)
        #pragma unroll
        for (int ni = 0; ni < 2; ni++)
          acc[mi][ni] = __builtin_amdgcn_mfma_f32_32x32x16_bf16(a[mi], bfr[ni], acc[mi][ni], 0, 0, 0);
    }
    __builtin_amdgcn_s_setprio(0);
  };

  stage(0, 0);
  stage(1, 1);                                 // 8 loads in flight
  for (int kt = 0; kt < 23; kt++) {
    int cur = kt & 1;
    asm volatile("s_waitcnt vmcnt(4)" ::: "memory");     // stage(kt) landed; stage(kt+1) in flight
    __builtin_amdgcn_sched_barrier(0);
    __builtin_amdgcn_s_barrier();
    compute(cur);
    asm volatile("s_waitcnt lgkmcnt(0)" ::: "memory");   // my ds_reads of buf[cur] done
    __builtin_amdgcn_sched_barrier(0);
    __builtin_amdgcn_s_barrier();
    if (kt + 2 < 24) stage(cur, kt + 2);
  }
  asm volatile("s_waitcnt vmcnt(0)" ::: "memory");
  __builtin_amdgcn_sched_barrier(0);
  __builtin_amdgcn_s_barrier();
  compute(1);                                  // kt = 23

  #pragma unroll
  for (int ni = 0; ni < 2; ni++) {
    int col = n0 + wc * 64 + ni * 32 + lo;
    float bias = out_b[col];
    #pragma unroll
    for (int mi = 0; mi < 2; mi++) {
      #pragma unroll
      for (int r = 0; r < 16; r++) {
        int row = m0 + wr * 64 + mi * 32 + (r & 3) + 8 * (r >> 2) + 4 * hi;
        out[(size_t)row * HID + col] = acc[mi][ni][r] + bias;
      }
    }
  }
}

extern "C" void kernel_launch(void* const* d_in, const int* in_sizes, int n_in,
                              void* d_out, int out_size, void* d_ws, size_t ws_size,
                              hipStream_t stream) {
  const float* hidden = (const float*)d_in[0];
  const float* lns    = (const float*)d_in[1];
  const float* lnb    = (const float*)d_in[2];
  const float* qkv_w  = (const float*)d_in[3];
  const float* qkv_b  = (const float*)d_in[4];
  const float* out_w  = (const float*)d_in[5];
  const float* out_b  = (const float*)d_in[6];
  char* ws = (char*)d_ws;
  unsigned short* qg  = (unsigned short*)(ws + 0);          // 16384*16*2      =   524288
  unsigned short* kg  = (unsigned short*)(ws + 524288);     // 16384*16*2      =   524288
  unsigned short* v16 = (unsigned short*)(ws + 1048576);    // 8*128*192*16*2  =  6291456
  unsigned short* qwb = (unsigned short*)(ws + 13631488);   // 208*192*2       =    79872
  unsigned short* wb  = (unsigned short*)(ws + 13711360);   // 768*768*2       =  1179648
  unsigned short* mg  = (unsigned short*)(ws + 14891008);   // 16384*768*2     = 25165824 (end 40056832)
  hipLaunchKernelGGL(k_prep,  dim3(615), dim3(256), 0, stream, qkv_w, out_w, qwb, wb);
  hipLaunchKernelGGL(k_lnqkv, dim3(256), dim3(256), 0, stream, hidden, lns, lnb, qwb, qkv_b,
                     mg, qg, kg, v16);
  hipLaunchKernelGGL(k_attn,  dim3(512), dim3(256), 0, stream, qg, kg, v16, mg);
  hipLaunchKernelGGL(k_out,   dim3(768), dim3(256), 0, stream, mg, wb, out_b, (float*)d_out);
}

// Round 15
// 96.773 us; speedup vs baseline: 1.1491x; 1.0148x over previous
//
#include <hip/hip_runtime.h>
#include <hip/hip_bf16.h>

#define HID 768
#define PD 164
#define NQ 196
#define SEQ 2048

typedef __attribute__((ext_vector_type(8))) short bf16x8_t;
typedef __attribute__((ext_vector_type(4))) float f32x4_t;
typedef __attribute__((ext_vector_type(16))) float f32x16_t;
typedef __attribute__((ext_vector_type(4))) unsigned int u32x4_t;

static __device__ __forceinline__ unsigned short f2bfu(float f) {
  union { __hip_bfloat16 h; unsigned short u; } cv;
  cv.h = __float2bfloat16(f);
  return cv.u;
}

static __device__ __forceinline__ unsigned cvtpk(float a, float b) {
  unsigned r;
  asm("v_cvt_pk_bf16_f32 %0, %1, %2" : "=v"(r) : "v"(a), "v"(b));
  return r;
}

static __device__ __forceinline__ void gload16(const void* g, void* l) {
  __builtin_amdgcn_global_load_lds(
      (const __attribute__((address_space(1))) void*)g,
      (__attribute__((address_space(3))) void*)l, 16, 0, 0);
}

// ---------------- prep: qkv_w -> bf16 (padded) only; wb conversion moved into k_lnqkv ----
__global__ __launch_bounds__(256) void k_prep_q(const float* __restrict__ qkv_w,
                                                unsigned short* __restrict__ qwb) {
  int i = (blockIdx.x * 256 + threadIdx.x) * 4;     // 208*192 = 39936 elems
  if (i >= 39936) return;
  int n = i / 192, k = i - n * 192;
  float v0 = (n < NQ && k + 0 < PD) ? qkv_w[n * PD + k + 0] : 0.f;
  float v1 = (n < NQ && k + 1 < PD) ? qkv_w[n * PD + k + 1] : 0.f;
  float v2 = (n < NQ && k + 2 < PD) ? qkv_w[n * PD + k + 2] : 0.f;
  float v3 = (n < NQ && k + 3 < PD) ? qkv_w[n * PD + k + 3] : 0.f;
  ushort4 o;
  o.x = f2bfu(v0); o.y = f2bfu(v1); o.z = f2bfu(v2); o.w = f2bfu(v3);
  *(ushort4*)(qwb + i) = o;
}

// ---------------- fused LN + x2 convert + QKV GEMM (+ wb convert blocks) ----------------
// blocks 0..255: LN + QKV as before. blocks 256..831: convert out_w -> wb bf16
// (rides in lnqkv's HBM-bound phase; consumer is k_out, two launches later).
__global__ __launch_bounds__(256, 2) void k_lnqkv(const float* __restrict__ hidden,
                                                  const float* __restrict__ lns,
                                                  const float* __restrict__ lnb,
                                                  const unsigned short* __restrict__ qwb,
                                                  const float* __restrict__ qkv_b,
                                                  const float* __restrict__ out_w,
                                                  unsigned short* __restrict__ wbo,
                                                  unsigned short* __restrict__ merged,
                                                  unsigned short* __restrict__ qg,
                                                  unsigned short* __restrict__ kg,
                                                  unsigned short* __restrict__ v16) {
  __shared__ float xr[64][172];
  __shared__ float stats[64][2];
  __shared__ unsigned short Aq[64][200];   // x1n bf16; cols 164..191 zero
  int t = threadIdx.x;
  if (blockIdx.x >= 256) {                 // ---- wb converter blocks ----
    int i = ((blockIdx.x - 256) * 256 + t) * 4;     // 768*768 = 589824 elems
    float4 v = *(const float4*)(out_w + i);
    ushort4 o;
    o.x = f2bfu(v.x); o.y = f2bfu(v.y); o.z = f2bfu(v.z); o.w = f2bfu(v.w);
    *(ushort4*)(wbo + i) = o;
    return;
  }
  int r0 = blockIdx.x * 64;
  #pragma unroll
  for (int i = 0; i < 11; i++) {
    int idx = t + i * 256;                 // 64 rows * 41 quads = 2624
    if (idx < 2624) {
      int row = idx / 41, q = idx - row * 41;
      float4 v = *(const float4*)(hidden + (size_t)(r0 + row) * HID + q * 4);
      *(float4*)&xr[row][q * 4] = v;
    }
  }
  __syncthreads();
  {
    int l = t & 63, w = t >> 6;
    int row = w * 16 + (l & 15), g = l >> 4;
    float sum = 0.f, sq = 0.f;
    #pragma unroll
    for (int j = 0; j < 41; j++) {
      float x = xr[row][g * 41 + j];
      sum += x; sq += x * x;
    }
    sum += __shfl_xor(sum, 16, 64); sum += __shfl_xor(sum, 32, 64);
    sq  += __shfl_xor(sq, 16, 64);  sq  += __shfl_xor(sq, 32, 64);
    float mean = sum * (1.f / PD);
    float var = sq * (1.f / PD) - mean * mean;
    float rstd = rsqrtf(var + 1e-5f);
    if (g == 0) { stats[row][0] = mean; stats[row][1] = rstd; }
  }
  __syncthreads();
  #pragma unroll
  for (int i = 0; i < 24; i++) {
    int idx = t + i * 256;                 // 64 rows * 96 pairs (192 cols)
    int row = idx / 96, c2 = idx - row * 96;
    int d = c2 * 2;
    float mean = stats[row][0], rstd = stats[row][1];
    float v0 = (d < PD)     ? (xr[row][d]     - mean) * rstd * lns[d]     + lnb[d]     : 0.f;
    float v1 = (d + 1 < PD) ? (xr[row][d + 1] - mean) * rstd * lns[d + 1] + lnb[d + 1] : 0.f;
    unsigned int pk = (unsigned int)f2bfu(v0) | ((unsigned int)f2bfu(v1) << 16);
    *(unsigned int*)(&Aq[row][d]) = pk;
  }
  #pragma unroll
  for (int i = 0; i < 38; i++) {
    int idx = t + i * 256;                 // 64 rows * 151 quads = 9664
    if (idx < 9664) {
      int row = idx / 151, q = idx - row * 151;
      int d = PD + q * 4;
      float4 v = *(const float4*)(hidden + (size_t)(r0 + row) * HID + d);
      ushort4 o;
      o.x = f2bfu(v.x); o.y = f2bfu(v.y); o.z = f2bfu(v.z); o.w = f2bfu(v.w);
      *(ushort4*)(merged + (size_t)(r0 + row) * HID + d) = o;
    }
  }
  __syncthreads();
  // ---- QKV GEMM: A from LDS, B from L2 ----
  int l = t & 63, w = t >> 6, lr15 = l & 15, g = l >> 4;
  f32x4_t acc[13];
  #pragma unroll
  for (int n = 0; n < 13; n++) acc[n] = (f32x4_t){0.f, 0.f, 0.f, 0.f};
  #pragma unroll 2
  for (int kc = 0; kc < 6; kc++) {
    bf16x8_t a = *(const bf16x8_t*)(&Aq[w * 16 + lr15][kc * 32 + g * 8]);
    #pragma unroll
    for (int n = 0; n < 13; n++) {
      bf16x8_t b = *(const bf16x8_t*)(qwb + (size_t)(n * 16 + lr15) * 192 + kc * 32 + g * 8);
      acc[n] = __builtin_amdgcn_mfma_f32_16x16x32_bf16(a, b, acc[n], 0, 0, 0);
    }
  }
  // ---- epilogue ----
  {
    float bias = qkv_b[lr15];
    #pragma unroll
    for (int r = 0; r < 4; r++) {
      int grow = r0 + w * 16 + g * 4 + r;
      qg[(size_t)grow * 16 + lr15] = f2bfu((acc[0][r] + bias) * 0.36067376022224085f); // 0.25*log2(e)
    }
  }
  {
    float bias = qkv_b[16 + lr15];
    #pragma unroll
    for (int r = 0; r < 4; r++) {
      int grow = r0 + w * 16 + g * 4 + r;
      kg[(size_t)grow * 16 + lr15] = f2bfu(acc[1][r] + bias);
    }
  }
  int s0 = (r0 & 2047) + w * 16;
  int bb = r0 >> 11;
  size_t vrowbase = (size_t)(bb * 128 + (s0 >> 4)) * 192;
  #pragma unroll
  for (int n = 2; n < 13; n++) {
    int col = n * 16 + lr15;
    int d = col - 32;                      // 0..175
    float bias = (col < NQ) ? qkv_b[col] : 0.f;
    float v0 = acc[n][0] + bias, v1 = acc[n][1] + bias;
    float v2 = acc[n][2] + bias, v3 = acc[n][3] + bias;
    if (d == 164) { v0 = v1 = v2 = v3 = 1.f; }        // ones row: free denominator
    else if (d >= PD) { v0 = v1 = v2 = v3 = 0.f; }
    ushort4 o;
    o.x = f2bfu(v0); o.y = f2bfu(v1); o.z = f2bfu(v2); o.w = f2bfu(v3);
    *(ushort4*)(v16 + (vrowbase + d) * 16 + g * 4) = o;
  }
}

// ---------------- flash attention v5 (proven, FROZEN) ----------------
__global__ __launch_bounds__(256, 2) void k_attn(const unsigned short* __restrict__ qg,
                                                 const unsigned short* __restrict__ kg,
                                                 const unsigned short* __restrict__ v16,
                                                 unsigned short* __restrict__ merged) {
  __shared__ float red[2][64 * 98];
  int t = threadIdx.x;
  int w = t >> 6, l = t & 63;
  int b = blockIdx.x & 7, qt = blockIdx.x >> 3;
  int lo = l & 31, hi = l >> 5;
  int qbase = b * SEQ + qt * 32;
  bf16x8_t qf = *(const bf16x8_t*)(qg + (size_t)(qbase + lo) * 16 + hi * 8);
  const unsigned short* kb = kg + (size_t)b * SEQ * 16;
  const unsigned short* vbb = v16 + (size_t)b * 128 * 192 * 16;
  f32x16_t zro;
  #pragma unroll
  for (int r = 0; r < 16; r++) zro[r] = 0.f;
  f32x16_t acc[6];
  #pragma unroll
  for (int f = 0; f < 6; f++) acc[f] = zro;

  int it0 = w * 8;
  bf16x8_t kf0 = *(const bf16x8_t*)(kb + (size_t)(it0 * 64 + lo) * 16 + hi * 8);
  bf16x8_t kf1 = *(const bf16x8_t*)(kb + (size_t)(it0 * 64 + 32 + lo) * 16 + hi * 8);
  bf16x8_t va[6], vb_[6];
  {
    const unsigned short* vt0 = vbb + (size_t)(it0 * 4) * (192 * 16) + hi * 8;
    #pragma unroll
    for (int f = 0; f < 6; f++) va[f] = *(const bf16x8_t*)(vt0 + (f * 32 + lo) * 16);
  }
  for (int it = it0; it < it0 + 8; ++it) {
    bf16x8_t nk0 = *(const bf16x8_t*)(kb + (size_t)((it + 1) * 64 + lo) * 16 + hi * 8);
    bf16x8_t nk1 = *(const bf16x8_t*)(kb + (size_t)((it + 1) * 64 + 32 + lo) * 16 + hi * 8);
    f32x16_t sc0 = __builtin_amdgcn_mfma_f32_32x32x16_bf16(kf0, qf, zro, 0, 0, 0);
    f32x16_t sc1 = __builtin_amdgcn_mfma_f32_32x32x16_bf16(kf1, qf, zro, 0, 0, 0);
    bf16x8_t pa[4];
    #pragma unroll
    for (int jt = 0; jt < 2; ++jt) {
      f32x16_t sc = jt ? sc1 : sc0;
      unsigned u[8];
      #pragma unroll
      for (int k = 0; k < 8; ++k)
        u[k] = cvtpk(exp2f(sc[2 * k]), exp2f(sc[2 * k + 1]));
      asm volatile("v_permlane32_swap_b32 %0, %1" : "+v"(u[0]), "+v"(u[2]));
      asm volatile("v_permlane32_swap_b32 %0, %1" : "+v"(u[1]), "+v"(u[3]));
      asm volatile("v_permlane32_swap_b32 %0, %1" : "+v"(u[4]), "+v"(u[6]));
      asm volatile("v_permlane32_swap_b32 %0, %1" : "+v"(u[5]), "+v"(u[7]));
      union { u32x4_t u4; bf16x8_t h8; } c0, c1;
      c0.u4 = (u32x4_t){u[0], u[1], u[2], u[3]};
      c1.u4 = (u32x4_t){u[4], u[5], u[6], u[7]};
      pa[jt * 2 + 0] = c0.h8;
      pa[jt * 2 + 1] = c1.h8;
    }
#define PV_STEP(JS, VCUR, VNXT, NT, NJS)                                            \
    {                                                                               \
      const unsigned short* vtn = vbb + (size_t)((NT) * 4 + (NJS)) * (192 * 16) + hi * 8; \
      _Pragma("unroll")                                                             \
      for (int f = 0; f < 6; f++) VNXT[f] = *(const bf16x8_t*)(vtn + (f * 32 + lo) * 16); \
      _Pragma("unroll")                                                             \
      for (int f = 0; f < 6; f++)                                                   \
        acc[f] = __builtin_amdgcn_mfma_f32_32x32x16_bf16(pa[JS], VCUR[f], acc[f], 0, 0, 0); \
    }
    PV_STEP(0, va,  vb_, it, 1)
    PV_STEP(1, vb_, va,  it, 2)
    PV_STEP(2, va,  vb_, it, 3)
    PV_STEP(3, vb_, va,  it + 1, 0)
#undef PV_STEP
    kf0 = nk0; kf1 = nk1;
  }

  if (w >= 2) {
    float* dst = &red[w - 2][l * 98];
    #pragma unroll
    for (int f = 0; f < 6; f++)
      #pragma unroll
      for (int r = 0; r < 16; r += 2)
        *(float2*)(dst + f * 16 + r) = make_float2(acc[f][r], acc[f][r + 1]);
  }
  __syncthreads();
  if (w < 2) {
    const float* src = &red[w][l * 98];
    #pragma unroll
    for (int f = 0; f < 6; f++)
      #pragma unroll
      for (int r = 0; r < 16; r += 2) {
        float2 v = *(const float2*)(src + f * 16 + r);
        acc[f][r] += v.x; acc[f][r + 1] += v.y;
      }
  }
  __syncthreads();
  if (w == 1) {
    float* dst = &red[0][l * 98];
    #pragma unroll
    for (int f = 0; f < 6; f++)
      #pragma unroll
      for (int r = 0; r < 16; r += 2)
        *(float2*)(dst + f * 16 + r) = make_float2(acc[f][r], acc[f][r + 1]);
  }
  __syncthreads();
  if (w == 0) {
    const float* src = &red[0][l * 98];
    #pragma unroll
    for (int f = 0; f < 6; f++)
      #pragma unroll
      for (int r = 0; r < 16; r += 2) {
        float2 v = *(const float2*)(src + f * 16 + r);
        acc[f][r] += v.x; acc[f][r + 1] += v.y;
      }
    float dninv[16];
    #pragma unroll
    for (int r = 0; r < 16; ++r)
      dninv[r] = 1.0f / __shfl(acc[5][r], 4 + hi * 32, 64);
    #pragma unroll
    for (int f = 0; f < 6; ++f) {
      int d = f * 32 + lo;
      if (d < PD) {
        #pragma unroll
        for (int r = 0; r < 16; ++r) {
          int q = qbase + (r & 3) + 8 * (r >> 2) + 4 * hi;
          merged[(size_t)q * HID + d] = f2bfu(acc[f][r] * dninv[r]);
        }
      }
    }
  }
}

// ---------------- out GEMM v5 (R11 exact, proven ~33us — FROZEN) --------------------
__global__ __launch_bounds__(256, 3) void k_out(const unsigned short* __restrict__ mg,
                                                const unsigned short* __restrict__ wb,
                                                const float* __restrict__ out_b,
                                                float* __restrict__ out) {
  __shared__ unsigned short Al[2][128 * 32];   // 16 KB
  __shared__ unsigned short Bl[2][128 * 32];   // 16 KB
  int t = threadIdx.x;
  int bid = blockIdx.x;
  int wgid = (bid & 7) * 96 + (bid >> 3);      // bijective: 768 = 8*96
  int nb = wgid % 6, mb = wgid / 6;
  int m0 = mb * 128, n0 = nb * 128;
  int l = t & 63, w = t >> 6, wr = w >> 1, wc = w & 1;
  int lr = l & 15, lg = l >> 4;
  int sw = (lr >> 1) & 3;
  f32x4_t acc[4][4];
  #pragma unroll
  for (int mi = 0; mi < 4; mi++)
    #pragma unroll
    for (int ni = 0; ni < 4; ni++) acc[mi][ni] = (f32x4_t){0.f, 0.f, 0.f, 0.f};

  auto stage = [&](int buf, int kt) {          // 2 A + 2 B gload16 per thread
    #pragma unroll
    for (int i = 0; i < 2; i++) {
      int off = t + i * 256;                   // 512 x 16B = 128x32 bf16
      int row = off >> 2, c = off & 3;
      int cs = c ^ ((row >> 1) & 3);           // inverse swizzle on SOURCE
      gload16(mg + (size_t)(m0 + row) * HID + kt * 32 + cs * 8, (char*)&Al[buf][0] + off * 16);
    }
    #pragma unroll
    for (int i = 0; i < 2; i++) {
      int off = t + i * 256;
      int row = off >> 2, c = off & 3;
      int cs = c ^ ((row >> 1) & 3);
      gload16(wb + (size_t)(n0 + row) * HID + kt * 32 + cs * 8, (char*)&Bl[buf][0] + off * 16);
    }
  };
  auto compute = [&](int cur) {                // 16 MFMAs (K=32 per step)
    __builtin_amdgcn_s_setprio(1);
    bf16x8_t a[4], bfr[4];
    int slot = lg ^ sw;
    #pragma unroll
    for (int mi = 0; mi < 4; mi++)
      a[mi] = *(const bf16x8_t*)(&Al[cur][(wr * 64 + mi * 16 + lr) * 32 + slot * 8]);
    #pragma unroll
    for (int ni = 0; ni < 4; ni++)
      bfr[ni] = *(const bf16x8_t*)(&Bl[cur][(wc * 64 + ni * 16 + lr) * 32 + slot * 8]);
    #pragma unroll
    for (int mi = 0; mi < 4; mi++)
      #pragma unroll
      for (int ni = 0; ni < 4; ni++)
        acc[mi][ni] = __builtin_amdgcn_mfma_f32_16x16x32_bf16(a[mi], bfr[ni], acc[mi][ni], 0, 0, 0);
    __builtin_amdgcn_s_setprio(0);
  };

  stage(0, 0);
  stage(1, 1);                                 // 8 loads in flight
  for (int kt = 0; kt < 23; kt++) {
    int cur = kt & 1;
    asm volatile("s_waitcnt vmcnt(4)" ::: "memory");     // stage(kt) landed; stage(kt+1) in flight
    __builtin_amdgcn_sched_barrier(0);
    __builtin_amdgcn_s_barrier();
    compute(cur);
    asm volatile("s_waitcnt lgkmcnt(0)" ::: "memory");   // my ds_reads of buf[cur] done
    __builtin_amdgcn_sched_barrier(0);
    __builtin_amdgcn_s_barrier();
    if (kt + 2 < 24) stage(cur, kt + 2);
  }
  asm volatile("s_waitcnt vmcnt(0)" ::: "memory");
  __builtin_amdgcn_sched_barrier(0);
  __builtin_amdgcn_s_barrier();
  compute(1);                                  // kt = 23

  #pragma unroll
  for (int ni = 0; ni < 4; ni++) {
    int col = n0 + wc * 64 + ni * 16 + lr;
    float bias = out_b[col];
    #pragma unroll
    for (int mi = 0; mi < 4; mi++) {
      #pragma unroll
      for (int r = 0; r < 4; r++) {
        int row = m0 + wr * 64 + mi * 16 + lg * 4 + r;
        out[(size_t)row * HID + col] = acc[mi][ni][r] + bias;
      }
    }
  }
}

extern "C" void kernel_launch(void* const* d_in, const int* in_sizes, int n_in,
                              void* d_out, int out_size, void* d_ws, size_t ws_size,
                              hipStream_t stream) {
  const float* hidden = (const float*)d_in[0];
  const float* lns    = (const float*)d_in[1];
  const float* lnb    = (const float*)d_in[2];
  const float* qkv_w  = (const float*)d_in[3];
  const float* qkv_b  = (const float*)d_in[4];
  const float* out_w  = (const float*)d_in[5];
  const float* out_b  = (const float*)d_in[6];
  char* ws = (char*)d_ws;
  unsigned short* qg  = (unsigned short*)(ws + 0);          // 16384*16*2      =   524288
  unsigned short* kg  = (unsigned short*)(ws + 524288);     // 16384*16*2      =   524288
  unsigned short* v16 = (unsigned short*)(ws + 1048576);    // 8*128*192*16*2  =  6291456
  unsigned short* qwb = (unsigned short*)(ws + 13631488);   // 208*192*2       =    79872
  unsigned short* wb  = (unsigned short*)(ws + 13711360);   // 768*768*2       =  1179648
  unsigned short* mg  = (unsigned short*)(ws + 14891008);   // 16384*768*2     = 25165824 (end 40056832)
  hipLaunchKernelGGL(k_prep_q, dim3(39),  dim3(256), 0, stream, qkv_w, qwb);
  hipLaunchKernelGGL(k_lnqkv,  dim3(832), dim3(256), 0, stream, hidden, lns, lnb, qwb, qkv_b,
                     out_w, wb, mg, qg, kg, v16);
  hipLaunchKernelGGL(k_attn,   dim3(512), dim3(256), 0, stream, qg, kg, v16, mg);
  hipLaunchKernelGGL(k_out,    dim3(768), dim3(256), 0, stream, mg, wb, out_b, (float*)d_out);
}